// Round 8
// baseline (361.721 us; speedup 1.0000x reference)
//
#include <hip/hip_runtime.h>

#define B 8
#define N 8192
#define M 2048
#define NITER 4
#define BASE_ALPHA 0.1f

#define NTHR 1024              // 16 waves (4 waves/SIMD)
#define NPT 32                 // point-lanes per split
#define NSPLIT 32              // j-splits per block
#define JS (M / NSPLIT)        // 64 y's per split
#define PT 8                   // points per thread
#define PPB (NPT * PT)         // 256 points per block
#define NBLK (B * N / PPB)     // 256 blocks = 1/CU (unconditionally co-resident)
#define BPB (NBLK / B)         // 32 blocks per batch

// ws: slots u64[NITER][B][BPB] = 8192 B, memsetAsync(0) per call.
// Distributed-slot barrier: block blk of batch b publishes (rawbits(blockmax)<<32)|(iter+1)
// to its OWN slot (release store, no RMW); every block's tid0 read-polls its batch's 32
// slots and computes the max locally. R6/R7's 2048 seq_cst RMWs/iter on ONE cache line
// (all 8 batch slots in 64 B) ping-ponged across 8 XCDs ≈ 200 us of stall — this has
// zero RMW contention and read-shared poll lines.
//
// Tile PHYSICAL layout transposed: logical y-index i = split*JS + j at tile[j*32+split].
// Pass-1 reads half-wave-uniform (broadcast, conflict-free); pass-2 ~4-way banked.

__device__ __forceinline__ unsigned int ord32(float t) {
    unsigned int u = __float_as_uint(t);
    return u ^ ((unsigned int)((int)u >> 31) | 0x80000000u);   // float order -> uint order
}
__device__ __forceinline__ float dec32(unsigned int h) {
    return __uint_as_float((h & 0x80000000u) ? (h ^ 0x80000000u) : ~h);
}

__global__ __launch_bounds__(NTHR, 4) void refine_all(const float* __restrict__ pred,
                                                      const float* __restrict__ partial,
                                                      unsigned long long* __restrict__ slots,
                                                      float* __restrict__ out) {
    __shared__ float4 tile[M];                     // {-2y0,-2y1,-2y2,|y|^2}, transposed phys
    __shared__ unsigned long long lkeys[16][PPB];  // 32 KB: per-wave (min_t, split) keys
    __shared__ float4 lpos[PPB];                   // {x,y,z,|r|^2}
    __shared__ float redbuf[4];                    // owner-wave block-max partials
    __shared__ float mxbuf;
    __shared__ unsigned int flag;

    const int tid = threadIdx.x;
    const int b = blockIdx.x >> 5;                 // 32 blocks per batch
    const int blk = blockIdx.x & 31;
    const int gp0 = b * N + blk * PPB;

    // Build y-tile once. Writes phys-contiguous; global reads 24 KB once (L2-resident).
    // (-2y)*x products bit-equal to reference's (-2x)*y.
    const float* pa = partial + b * M * 3;
    for (int u = tid; u < M; u += NTHR) {
        int sp = u & (NSPLIT - 1);                 // phys u = jj*32 + sp
        int jj = u >> 5;
        int i = sp * JS + jj;                      // logical index
        float y0 = pa[i * 3 + 0], y1 = pa[i * 3 + 1], y2 = pa[i * 3 + 2];
        tile[u] = make_float4(-2.0f * y0, -2.0f * y1, -2.0f * y2,
                              y0 * y0 + y1 * y1 + y2 * y2);
    }
    if (tid == 0) flag = 0u;
    if (tid < PPB) {
        const float* pp = pred + (unsigned long long)(gp0 + tid) * 3;
        float x = pp[0], y = pp[1], z = pp[2];
        lpos[tid] = make_float4(x, y, z, x * x + y * y + z * z);
    }
    __syncthreads();

    const int split = tid >> 5;                    // 0..31 (uniform per half-wave)
    const int pt = tid & 31;
    const int wave = tid >> 6;                     // 0..15
    const float4* __restrict__ qs = tile + split;  // qs[j*32] = logical (split, j)

    for (int iter = 0; iter < NITER; ++iter) {
        // ---- pass 1: per-split MIN VALUE only (3.5 VALU/pair) ----
        float x0[PT], x1[PT], x2[PT];
        #pragma unroll
        for (int k = 0; k < PT; ++k) {
            float4 r = lpos[pt + k * NPT];
            x0[k] = r.x; x1[k] = r.y; x2[k] = r.z;
        }
        float vb[PT];
        #pragma unroll
        for (int k = 0; k < PT; ++k) vb[k] = 3.402823466e+38f;

        #pragma unroll 4
        for (int j = 0; j < JS; j += 2) {
            float4 q0 = qs[j * NSPLIT];
            float4 q1 = qs[(j + 1) * NSPLIT];
            #pragma unroll
            for (int k = 0; k < PT; ++k) {
                float t0 = fmaf(x0[k], q0.x, fmaf(x1[k], q0.y, fmaf(x2[k], q0.z, q0.w)));
                float t1 = fmaf(x0[k], q1.x, fmaf(x1[k], q1.y, fmaf(x2[k], q1.z, q1.w)));
                vb[k] = fminf(fminf(t0, t1), vb[k]);   // v_min3_f32
            }
        }

        // ---- merge (value, split) across the wave's two splits, write per-wave row ----
        #pragma unroll
        for (int k = 0; k < PT; ++k) {
            unsigned int hi = ord32(vb[k]);
            unsigned int lo = (unsigned int)split;
            unsigned int ohi = __shfl_xor(hi, 32), olo = __shfl_xor(lo, 32);
            if (ohi < hi || (ohi == hi && olo < lo)) { hi = ohi; lo = olo; }  // lex min
            if ((tid & 32) == 0)
                lkeys[wave][pt + k * NPT] = (((unsigned long long)hi) << 32) | lo;
        }
        __syncthreads();                            // sync A: lkeys ready

        // ---- owners (tid<256): reduce rows, wave-max -> redbuf ----
        int bsplit = 0; float tstar = 0.f, md = 0.f; float4 f4 = make_float4(0, 0, 0, 0);
        if (tid < PPB) {
            unsigned long long best = lkeys[0][tid];
            #pragma unroll
            for (int r = 1; r < 16; ++r) {
                unsigned long long c = lkeys[r][tid];
                if (c < best) best = c;
            }
            bsplit = (int)(unsigned int)(best & 0xFFFFFFFFull);
            tstar = dec32((unsigned int)(best >> 32));
            f4 = lpos[tid];
            md = sqrtf(fmaxf(f4.w + tstar, 0.0f));
            float wm = md;
            for (int o = 32; o > 0; o >>= 1) wm = fmaxf(wm, __shfl_down(wm, o));
            if ((tid & 63) == 0) redbuf[tid >> 6] = wm;
        }
        __syncthreads();                            // sync A2: redbuf ready

        // ---- tid0: publish block max to own slot (no RMW) ----
        if (tid == 0) {
            float bm = fmaxf(fmaxf(redbuf[0], redbuf[1]), fmaxf(redbuf[2], redbuf[3]));
            unsigned long long v = (((unsigned long long)__float_as_uint(bm)) << 32)
                                   | (unsigned int)(iter + 1);
            __hip_atomic_store(&slots[(iter * B + b) * BPB + blk], v,
                               __ATOMIC_RELEASE, __HIP_MEMORY_SCOPE_AGENT);
        }

        // ---- pass 2 (overlaps publish->poll window): exact first-argmin in winning
        //      split — bit-identical fmaf chain to pass 1 ----
        float4 nr = make_float4(0, 0, 0, 0);
        if (tid < PPB) {
            const float4* __restrict__ q2 = tile + bsplit;
            float bt = 3.402823466e+38f; int bj = 0;
            #pragma unroll 4
            for (int j = 0; j < JS; ++j) {
                float4 q = q2[j * NSPLIT];
                float t = fmaf(f4.x, q.x, fmaf(f4.y, q.y, fmaf(f4.z, q.z, q.w)));
                if (t < bt) { bt = t; bj = j; }     // strict < keeps earliest j
            }
            nr = tile[bj * NSPLIT + bsplit];
        }

        // ---- tid0: read-poll the batch's 32 slots, compute max locally ----
        if (tid == 0) {
            const unsigned long long* sl = &slots[(iter * B + b) * BPB];
            const unsigned int tag = (unsigned int)(iter + 1);
            unsigned int mxu = 0;
            for (;;) {
                bool done = true; mxu = 0;
                for (int i = 0; i < BPB; ++i) {
                    unsigned long long v = __hip_atomic_load(&sl[i], __ATOMIC_ACQUIRE,
                                                             __HIP_MEMORY_SCOPE_AGENT);
                    if ((unsigned int)v != tag) { done = false; break; }
                    unsigned int hv = (unsigned int)(v >> 32);
                    if (hv > mxu) mxu = hv;         // md >= 0: raw-bit order == float order
                }
                if (done) break;
                __builtin_amdgcn_s_sleep(2);
            }
            mxbuf = __uint_as_float(mxu);
            __hip_atomic_store(&flag, (unsigned int)(iter + 1),
                               __ATOMIC_RELEASE, __HIP_MEMORY_SCOPE_WORKGROUP);
        }
        if (tid < PPB && wave != 0) {
            while (__hip_atomic_load(&flag, __ATOMIC_ACQUIRE,
                                     __HIP_MEMORY_SCOPE_WORKGROUP) < (unsigned int)(iter + 1))
                __builtin_amdgcn_s_sleep(1);
        }

        // ---- owners: apply update ----
        if (tid < PPB) {
            const float mx = mxbuf;                 // wave0: same-wave DS order; others: after acquire
            const float inv = 1.0f / (mx + 1e-6f);
            const float alpha = BASE_ALPHA * (2.0f - md * inv);
            const float ny0 = -0.5f * nr.x, ny1 = -0.5f * nr.y, ny2 = -0.5f * nr.z;  // exact
            const float rx = fmaf(alpha, ny0 - f4.x, f4.x);
            const float ry = fmaf(alpha, ny1 - f4.y, f4.y);
            const float rz = fmaf(alpha, ny2 - f4.z, f4.z);
            if (iter == NITER - 1) {
                float* po = out + (unsigned long long)(gp0 + tid) * 3;
                po[0] = rx; po[1] = ry; po[2] = rz;
            } else {
                lpos[tid] = make_float4(rx, ry, rz, rx * rx + ry * ry + rz * rz);
            }
        }
        __syncthreads();                            // sync B: lpos ready for next scan
    }
}

extern "C" void kernel_launch(void* const* d_in, const int* in_sizes, int n_in,
                              void* d_out, int out_size, void* d_ws, size_t ws_size,
                              hipStream_t stream) {
    const float* pred = (const float*)d_in[0];
    const float* partial = (const float*)d_in[1];
    unsigned long long* slots = (unsigned long long*)d_ws;
    float* out = (float*)d_out;

    hipMemsetAsync(slots, 0, NITER * B * BPB * sizeof(unsigned long long), stream);

    void* args[] = {(void*)&pred, (void*)&partial, (void*)&slots, (void*)&out};
    hipLaunchCooperativeKernel((const void*)refine_all, dim3(NBLK), dim3(NTHR),
                               args, 0, stream);
}

// Round 9
// 120.028 us; speedup vs baseline: 3.0136x; 3.0136x over previous
//
#include <hip/hip_runtime.h>

#define B 8
#define N 8192
#define M 2048
#define NITER 4
#define BASE_ALPHA 0.1f

#define NTHR 1024              // 16 waves (4 waves/SIMD, 1 block/CU)
#define NPT 32                 // point-lanes per split
#define NSPLIT 32              // j-splits per block
#define JS (M / NSPLIT)        // 64 y's per split
#define PT 8                   // points per thread
#define PPB (NPT * PT)         // 256 points per block
#define NBLK (B * N / PPB)     // 256 blocks
#define BPB (NBLK / B)         // 32 blocks per batch

// Kernel boundaries are the cross-block barrier (R6-R8 lesson: every in-kernel
// cross-block sync variant — RMW counter, slot poll — cost ~200 us of stall).
// ws: pos4 float4[B*N] @0 (1 MB) = refined_k {x,y,z,|r|^2}
//     aux  uint2 [B*N] @1 MB (512 KB) = (bits(md_k), phys tile idx of nearest)
//     slots float[B][BPB] @1.5 MB (1 KB) = per-block partial max of md_k
// No memset needed: slots/pos4/aux are always fully written before being read.
#define OFF_AUX   (1024 * 1024)
#define OFF_SLOTS (1536 * 1024)

// Tile PHYSICAL layout transposed: logical y-index i = split*JS + j at tile[j*32+split].
// Pass-1 reads are half-wave-uniform (broadcast, conflict-free); pass-2 ~4-way banked.

__device__ __forceinline__ unsigned int ord32(float t) {
    unsigned int u = __float_as_uint(t);
    return u ^ ((unsigned int)((int)u >> 31) | 0x80000000u);   // float order -> uint order
}
__device__ __forceinline__ float dec32(unsigned int h) {
    return __uint_as_float((h & 0x80000000u) ? (h ^ 0x80000000u) : ~h);
}

__global__ __launch_bounds__(NTHR, 4) void iter_kernel(const float* __restrict__ pred,
                                                       const float* __restrict__ partial,
                                                       float4* __restrict__ pos4,
                                                       uint2* __restrict__ aux,
                                                       float* __restrict__ slots,
                                                       int iter) {
    __shared__ float4 tile[M];                     // {-2y0,-2y1,-2y2,|y|^2}, transposed phys
    __shared__ unsigned long long lkeys[16][PPB];  // 32 KB: per-wave (min_t, split) keys
    __shared__ float4 lpos[PPB];                   // {x,y,z,|r|^2}
    __shared__ float redbuf[4];
    __shared__ float mxsh;

    const int tid = threadIdx.x;
    const int b = blockIdx.x >> 5;                 // 32 blocks per batch
    const int blk = blockIdx.x & 31;
    const int gp0 = b * N + blk * PPB;

    // Build y-tile. Writes phys-contiguous; (-2y)*x bit-equal to reference's (-2x)*y.
    const float* pa = partial + b * M * 3;
    for (int u = tid; u < M; u += NTHR) {
        int sp = u & (NSPLIT - 1);                 // phys u = jj*32 + sp
        int jj = u >> 5;
        int i = sp * JS + jj;                      // logical index
        float y0 = pa[i * 3 + 0], y1 = pa[i * 3 + 1], y2 = pa[i * 3 + 2];
        tile[u] = make_float4(-2.0f * y0, -2.0f * y1, -2.0f * y2,
                              y0 * y0 + y1 * y1 + y2 * y2);
    }
    // Batch max of previous iteration from the 32 slots (complete: kernel boundary).
    if (iter > 0 && tid < 64) {
        float v = slots[b * BPB + (tid & 31)];     // replicated across both half-waves
        #pragma unroll
        for (int o = 16; o > 0; o >>= 1) v = fmaxf(v, __shfl_xor(v, o));
        if (tid == 0) mxsh = v;
    }
    __syncthreads();

    // Owners: produce refined_k, stash to lpos (for scan) and pos4 (for next kernel).
    if (tid < PPB) {
        const int p = gp0 + tid;
        float rx, ry, rz;
        if (iter == 0) {
            const float* pp = pred + (unsigned long long)p * 3;
            rx = pp[0]; ry = pp[1]; rz = pp[2];
        } else {
            float4 f = pos4[p];
            uint2 a = aux[p];
            float md = __uint_as_float(a.x);
            float4 nr = tile[a.y];                 // phys idx; tile content identical each iter
            float inv = 1.0f / (mxsh + 1e-6f);
            float alpha = BASE_ALPHA * (2.0f - md * inv);
            const float ny0 = -0.5f * nr.x, ny1 = -0.5f * nr.y, ny2 = -0.5f * nr.z;  // exact y
            rx = fmaf(alpha, ny0 - f.x, f.x);
            ry = fmaf(alpha, ny1 - f.y, f.y);
            rz = fmaf(alpha, ny2 - f.z, f.z);
        }
        float w = rx * rx + ry * ry + rz * rz;
        lpos[tid] = make_float4(rx, ry, rz, w);
        pos4[p] = make_float4(rx, ry, rz, w);
    }
    __syncthreads();

    const int split = tid >> 5;                    // 0..31 (uniform per half-wave)
    const int pt = tid & 31;
    const int wave = tid >> 6;                     // 0..15
    const float4* __restrict__ qs = tile + split;  // qs[j*32] = logical (split, j)

    // ---- pass 1: per-split MIN VALUE only (3.5 VALU/pair) ----
    float x0[PT], x1[PT], x2[PT];
    #pragma unroll
    for (int k = 0; k < PT; ++k) {
        float4 r = lpos[pt + k * NPT];
        x0[k] = r.x; x1[k] = r.y; x2[k] = r.z;
    }
    float vb[PT];
    #pragma unroll
    for (int k = 0; k < PT; ++k) vb[k] = 3.402823466e+38f;

    #pragma unroll 4
    for (int j = 0; j < JS; j += 2) {
        float4 q0 = qs[j * NSPLIT];
        float4 q1 = qs[(j + 1) * NSPLIT];
        #pragma unroll
        for (int k = 0; k < PT; ++k) {
            float t0 = fmaf(x0[k], q0.x, fmaf(x1[k], q0.y, fmaf(x2[k], q0.z, q0.w)));
            float t1 = fmaf(x0[k], q1.x, fmaf(x1[k], q1.y, fmaf(x2[k], q1.z, q1.w)));
            vb[k] = fminf(fminf(t0, t1), vb[k]);   // v_min3_f32
        }
    }

    // ---- merge (value, split) across the wave's two splits, write per-wave row ----
    #pragma unroll
    for (int k = 0; k < PT; ++k) {
        unsigned int hi = ord32(vb[k]);
        unsigned int lo = (unsigned int)split;
        unsigned int ohi = __shfl_xor(hi, 32), olo = __shfl_xor(lo, 32);
        if (ohi < hi || (ohi == hi && olo < lo)) { hi = ohi; lo = olo; }  // lex min
        if ((tid & 32) == 0)
            lkeys[wave][pt + k * NPT] = (((unsigned long long)hi) << 32) | lo;
    }
    __syncthreads();

    // ---- owners: reduce 16 rows, pass-2 exact first-argmin in winning split ----
    if (tid < PPB) {
        unsigned long long best = lkeys[0][tid];
        #pragma unroll
        for (int r = 1; r < 16; ++r) {
            unsigned long long c = lkeys[r][tid];
            if (c < best) best = c;
        }
        const int bsplit = (int)(unsigned int)(best & 0xFFFFFFFFull);
        const float tstar = dec32((unsigned int)(best >> 32));
        const float4 f4 = lpos[tid];
        const float md = sqrtf(fmaxf(f4.w + tstar, 0.0f));

        // pass 2: bit-identical fmaf chain; strict < keeps earliest j (lowest logical idx)
        const float4* __restrict__ q2 = tile + bsplit;
        float bt = 3.402823466e+38f; int bj = 0;
        #pragma unroll 4
        for (int j = 0; j < JS; ++j) {
            float4 q = q2[j * NSPLIT];
            float t = fmaf(f4.x, q.x, fmaf(f4.y, q.y, fmaf(f4.z, q.z, q.w)));
            if (t < bt) { bt = t; bj = j; }
        }
        aux[gp0 + tid] = make_uint2(__float_as_uint(md),
                                    (unsigned int)(bj * NSPLIT + bsplit));  // phys idx

        float wm = md;
        for (int o = 32; o > 0; o >>= 1) wm = fmaxf(wm, __shfl_down(wm, o));
        if ((tid & 63) == 0) redbuf[tid >> 6] = wm;
    }
    __syncthreads();
    if (tid == 0)
        slots[b * BPB + blk] = fmaxf(fmaxf(redbuf[0], redbuf[1]),
                                     fmaxf(redbuf[2], redbuf[3]));
}

__global__ __launch_bounds__(256) void final_kernel(const float* __restrict__ partial,
                                                    const float4* __restrict__ pos4,
                                                    const uint2* __restrict__ aux,
                                                    const float* __restrict__ slots,
                                                    float* __restrict__ out) {
    __shared__ float mxsh;
    const int p = blockIdx.x * 256 + threadIdx.x;  // 65536 points; batch uniform per block
    const int b = p >> 13;
    if (threadIdx.x < 64) {
        float v = slots[b * BPB + (threadIdx.x & 31)];
        #pragma unroll
        for (int o = 16; o > 0; o >>= 1) v = fmaxf(v, __shfl_xor(v, o));
        if (threadIdx.x == 0) mxsh = v;
    }
    __syncthreads();
    float4 f = pos4[p];
    uint2 a = aux[p];
    float md = __uint_as_float(a.x);
    int phys = (int)a.y;
    int logical = (phys & (NSPLIT - 1)) * JS + (phys >> 5);
    const float* py = partial + ((unsigned long long)(b * M + logical)) * 3;
    float y0 = py[0], y1 = py[1], y2 = py[2];      // same bits as -0.5*(-2y) in iter path
    float inv = 1.0f / (mxsh + 1e-6f);
    float alpha = BASE_ALPHA * (2.0f - md * inv);
    float* po = out + (unsigned long long)p * 3;
    po[0] = fmaf(alpha, y0 - f.x, f.x);
    po[1] = fmaf(alpha, y1 - f.y, f.y);
    po[2] = fmaf(alpha, y2 - f.z, f.z);
}

extern "C" void kernel_launch(void* const* d_in, const int* in_sizes, int n_in,
                              void* d_out, int out_size, void* d_ws, size_t ws_size,
                              hipStream_t stream) {
    const float* pred = (const float*)d_in[0];
    const float* partial = (const float*)d_in[1];
    char* ws = (char*)d_ws;
    float4* pos4 = (float4*)ws;
    uint2* aux = (uint2*)(ws + OFF_AUX);
    float* slots = (float*)(ws + OFF_SLOTS);
    float* out = (float*)d_out;

    for (int it = 0; it < NITER; ++it)
        hipLaunchKernelGGL(iter_kernel, dim3(NBLK), dim3(NTHR), 0, stream,
                           pred, partial, pos4, aux, slots, it);
    hipLaunchKernelGGL(final_kernel, dim3(B * N / 256), dim3(256), 0, stream,
                       partial, pos4, aux, slots, out);
}

// Round 10
// 118.633 us; speedup vs baseline: 3.0491x; 1.0118x over previous
//
#include <hip/hip_runtime.h>

#define B 8
#define N 8192
#define M 2048
#define NITER 4
#define BASE_ALPHA 0.1f

#define NTHR 1024              // 16 waves (4 waves/SIMD, 1 block/CU)
#define NPT 32                 // point-lanes per split
#define NSPLIT 32              // j-splits per block
#define JS (M / NSPLIT)        // 64 y's per split
#define JQ (JS / 4)            // 16 j-quads per split
#define PT 8                   // points per thread
#define PPB (NPT * PT)         // 256 points per block
#define NBLK (B * N / PPB)     // 256 blocks
#define BPB (NBLK / B)         // 32 blocks per batch

// Kernel boundaries are the cross-block barrier (R6-R8: every in-kernel cross-block
// sync variant cost ~200 us). ws: pos4 float4[B*N] @0; aux uint2[B*N] @1MB
// (bits(md), LOGICAL nearest idx); slots float[B][BPB] @1.5MB. No memset needed.
#define OFF_AUX   (1024 * 1024)
#define OFF_SLOTS (1536 * 1024)

// LDS tile is SoA-by-4: for split sp, j-quad jq, component arrays
// sX/sY/sZ/sW[jq*32+sp] hold {comp(j=4jq..4jq+3)} with x/y/z pre-scaled by -2 and
// w = |y|^2. b128 loads land as two pk-aligned f32 pairs -> v_pk_fma_f32 path
// (2 FMAs/lane/instr; scalar fmaf caps at half the 157 TF vector peak).

typedef float f2 __attribute__((ext_vector_type(2)));

__device__ __forceinline__ unsigned int ord32(float t) {
    unsigned int u = __float_as_uint(t);
    return u ^ ((unsigned int)((int)u >> 31) | 0x80000000u);   // float order -> uint order
}
__device__ __forceinline__ float dec32(unsigned int h) {
    return __uint_as_float((h & 0x80000000u) ? (h ^ 0x80000000u) : ~h);
}

__global__ __launch_bounds__(NTHR, 4) void iter_kernel(const float* __restrict__ pred,
                                                       const float* __restrict__ partial,
                                                       float4* __restrict__ pos4,
                                                       uint2* __restrict__ aux,
                                                       float* __restrict__ slots,
                                                       int iter) {
    __shared__ float4 sX[M / 4], sY[M / 4], sZ[M / 4], sW[M / 4];  // 32 KB
    __shared__ unsigned long long lkeys[16][PPB];                  // 32 KB
    __shared__ float4 lpos[PPB];
    __shared__ float redbuf[4];
    __shared__ float mxsh;

    const int tid = threadIdx.x;
    const int b = blockIdx.x >> 5;
    const int blk = blockIdx.x & 31;
    const int gp0 = b * N + blk * PPB;

    // Build SoA tile. (-2y)*x bit-equal to reference's (-2x)*y.
    const float* pa = partial + b * M * 3;
    if (tid < M / 4) {
        int sp = tid & 31, jq = tid >> 5;
        const float* p0 = pa + (sp * JS + jq * 4) * 3;
        float a0 = p0[0], a1 = p0[1],  a2 = p0[2];
        float b0 = p0[3], b1 = p0[4],  b2 = p0[5];
        float c0 = p0[6], c1 = p0[7],  c2 = p0[8];
        float d0 = p0[9], d1 = p0[10], d2 = p0[11];
        sX[tid] = make_float4(-2.f * a0, -2.f * b0, -2.f * c0, -2.f * d0);
        sY[tid] = make_float4(-2.f * a1, -2.f * b1, -2.f * c1, -2.f * d1);
        sZ[tid] = make_float4(-2.f * a2, -2.f * b2, -2.f * c2, -2.f * d2);
        sW[tid] = make_float4(a0 * a0 + a1 * a1 + a2 * a2, b0 * b0 + b1 * b1 + b2 * b2,
                              c0 * c0 + c1 * c1 + c2 * c2, d0 * d0 + d1 * d1 + d2 * d2);
    }
    // Batch max of previous iteration (complete: kernel boundary).
    if (iter > 0 && tid < 64) {
        float v = slots[b * BPB + (tid & 31)];
        #pragma unroll
        for (int o = 16; o > 0; o >>= 1) v = fmaxf(v, __shfl_xor(v, o));
        if (tid == 0) mxsh = v;
    }
    __syncthreads();

    // Owners: produce refined_k into lpos (scan) and pos4 (next kernel).
    if (tid < PPB) {
        const int p = gp0 + tid;
        float rx, ry, rz;
        if (iter == 0) {
            const float* pp = pred + (unsigned long long)p * 3;
            rx = pp[0]; ry = pp[1]; rz = pp[2];
        } else {
            float4 f = pos4[p];
            uint2 a = aux[p];
            float md = __uint_as_float(a.x);
            int lg = (int)a.y;                     // logical nearest idx
            int bs = lg >> 6, bj = lg & 63;
            int i4 = ((bj >> 2) * 32 + bs) * 4 + (bj & 3);
            float ny0 = -0.5f * ((const float*)sX)[i4];    // exact y bits
            float ny1 = -0.5f * ((const float*)sY)[i4];
            float ny2 = -0.5f * ((const float*)sZ)[i4];
            float inv = 1.0f / (mxsh + 1e-6f);
            float alpha = BASE_ALPHA * (2.0f - md * inv);
            rx = fmaf(alpha, ny0 - f.x, f.x);
            ry = fmaf(alpha, ny1 - f.y, f.y);
            rz = fmaf(alpha, ny2 - f.z, f.z);
        }
        float w = rx * rx + ry * ry + rz * rz;
        lpos[tid] = make_float4(rx, ry, rz, w);
        pos4[p] = make_float4(rx, ry, rz, w);
    }
    __syncthreads();

    const int split = tid >> 5;                    // 0..31 (uniform per half-wave)
    const int pt = tid & 31;
    const int wave = tid >> 6;

    // ---- pass 1: packed-f32 per-split min (2.0 VALU-instr/pair) ----
    f2 sx[PT], sy[PT], sz[PT];
    #pragma unroll
    for (int k = 0; k < PT; ++k) {
        float4 r = lpos[pt + k * NPT];
        sx[k] = (f2){r.x, r.x}; sy[k] = (f2){r.y, r.y}; sz[k] = (f2){r.z, r.z};
    }
    f2 acc[PT];
    #pragma unroll
    for (int k = 0; k < PT; ++k) acc[k] = (f2){3.402823466e+38f, 3.402823466e+38f};

    #pragma unroll 2
    for (int jq = 0; jq < JQ; ++jq) {
        float4 qx = sX[jq * 32 + split], qy = sY[jq * 32 + split];
        float4 qz = sZ[jq * 32 + split], qw = sW[jq * 32 + split];
        f2 qx01 = (f2){qx.x, qx.y}, qx23 = (f2){qx.z, qx.w};
        f2 qy01 = (f2){qy.x, qy.y}, qy23 = (f2){qy.z, qy.w};
        f2 qz01 = (f2){qz.x, qz.y}, qz23 = (f2){qz.z, qz.w};
        f2 qw01 = (f2){qw.x, qw.y}, qw23 = (f2){qw.z, qw.w};
        #pragma unroll
        for (int k = 0; k < PT; ++k) {
            f2 t01 = __builtin_elementwise_fma(sx[k], qx01,
                     __builtin_elementwise_fma(sy[k], qy01,
                     __builtin_elementwise_fma(sz[k], qz01, qw01)));
            f2 t23 = __builtin_elementwise_fma(sx[k], qx23,
                     __builtin_elementwise_fma(sy[k], qy23,
                     __builtin_elementwise_fma(sz[k], qz23, qw23)));
            acc[k] = __builtin_elementwise_min(acc[k],
                     __builtin_elementwise_min(t01, t23));     // exact, order-invariant
        }
    }

    // ---- merge (value, split) across the wave's two splits ----
    #pragma unroll
    for (int k = 0; k < PT; ++k) {
        float vbk = fminf(acc[k].x, acc[k].y);
        unsigned int hi = ord32(vbk);
        unsigned int lo = (unsigned int)split;
        unsigned int ohi = __shfl_xor(hi, 32), olo = __shfl_xor(lo, 32);
        if (ohi < hi || (ohi == hi && olo < lo)) { hi = ohi; lo = olo; }  // lex min
        if ((tid & 32) == 0)
            lkeys[wave][pt + k * NPT] = (((unsigned long long)hi) << 32) | lo;
    }
    __syncthreads();

    // ---- owners: reduce 16 rows, pass-2 exact first-argmin in winning split ----
    if (tid < PPB) {
        unsigned long long best = lkeys[0][tid];
        #pragma unroll
        for (int r = 1; r < 16; ++r) {
            unsigned long long c = lkeys[r][tid];
            if (c < best) best = c;
        }
        const int bsplit = (int)(unsigned int)(best & 0xFFFFFFFFull);
        const float tstar = dec32((unsigned int)(best >> 32));
        const float4 f4 = lpos[tid];
        const float md = sqrtf(fmaxf(f4.w + tstar, 0.0f));

        // pass 2: scalar fmaf chain bit-identical to pk halves; earliest j wins.
        float bt = 3.402823466e+38f; int bj = 0;
        for (int jq = 0; jq < JQ; ++jq) {
            float4 qx = sX[jq * 32 + bsplit], qy = sY[jq * 32 + bsplit];
            float4 qz = sZ[jq * 32 + bsplit], qw = sW[jq * 32 + bsplit];
            float t0 = fmaf(f4.x, qx.x, fmaf(f4.y, qy.x, fmaf(f4.z, qz.x, qw.x)));
            float t1 = fmaf(f4.x, qx.y, fmaf(f4.y, qy.y, fmaf(f4.z, qz.y, qw.y)));
            float t2 = fmaf(f4.x, qx.z, fmaf(f4.y, qy.z, fmaf(f4.z, qz.z, qw.z)));
            float t3 = fmaf(f4.x, qx.w, fmaf(f4.y, qy.w, fmaf(f4.z, qz.w, qw.w)));
            if (t0 < bt) { bt = t0; bj = jq * 4 + 0; }
            if (t1 < bt) { bt = t1; bj = jq * 4 + 1; }
            if (t2 < bt) { bt = t2; bj = jq * 4 + 2; }
            if (t3 < bt) { bt = t3; bj = jq * 4 + 3; }
        }
        aux[gp0 + tid] = make_uint2(__float_as_uint(md),
                                    (unsigned int)(bsplit * JS + bj));   // logical idx

        float wm = md;
        for (int o = 32; o > 0; o >>= 1) wm = fmaxf(wm, __shfl_down(wm, o));
        if ((tid & 63) == 0) redbuf[tid >> 6] = wm;
    }
    __syncthreads();
    if (tid == 0)
        slots[b * BPB + blk] = fmaxf(fmaxf(redbuf[0], redbuf[1]),
                                     fmaxf(redbuf[2], redbuf[3]));
}

__global__ __launch_bounds__(256) void final_kernel(const float* __restrict__ partial,
                                                    const float4* __restrict__ pos4,
                                                    const uint2* __restrict__ aux,
                                                    const float* __restrict__ slots,
                                                    float* __restrict__ out) {
    __shared__ float mxsh;
    const int p = blockIdx.x * 256 + threadIdx.x;  // batch uniform per block
    const int b = p >> 13;
    if (threadIdx.x < 64) {
        float v = slots[b * BPB + (threadIdx.x & 31)];
        #pragma unroll
        for (int o = 16; o > 0; o >>= 1) v = fmaxf(v, __shfl_xor(v, o));
        if (threadIdx.x == 0) mxsh = v;
    }
    __syncthreads();
    float4 f = pos4[p];
    uint2 a = aux[p];
    float md = __uint_as_float(a.x);
    const float* py = partial + ((unsigned long long)(b * M + (int)a.y)) * 3;
    float y0 = py[0], y1 = py[1], y2 = py[2];      // same bits as -0.5*(-2y)
    float inv = 1.0f / (mxsh + 1e-6f);
    float alpha = BASE_ALPHA * (2.0f - md * inv);
    float* po = out + (unsigned long long)p * 3;
    po[0] = fmaf(alpha, y0 - f.x, f.x);
    po[1] = fmaf(alpha, y1 - f.y, f.y);
    po[2] = fmaf(alpha, y2 - f.z, f.z);
}

extern "C" void kernel_launch(void* const* d_in, const int* in_sizes, int n_in,
                              void* d_out, int out_size, void* d_ws, size_t ws_size,
                              hipStream_t stream) {
    const float* pred = (const float*)d_in[0];
    const float* partial = (const float*)d_in[1];
    char* ws = (char*)d_ws;
    float4* pos4 = (float4*)ws;
    uint2* aux = (uint2*)(ws + OFF_AUX);
    float* slots = (float*)(ws + OFF_SLOTS);
    float* out = (float*)d_out;

    for (int it = 0; it < NITER; ++it)
        hipLaunchKernelGGL(iter_kernel, dim3(NBLK), dim3(NTHR), 0, stream,
                           pred, partial, pos4, aux, slots, it);
    hipLaunchKernelGGL(final_kernel, dim3(B * N / 256), dim3(256), 0, stream,
                       partial, pos4, aux, slots, out);
}